// Round 9
// baseline (635.271 us; speedup 1.0000x reference)
//
#include <hip/hip_runtime.h>
#include <hip/hip_bf16.h>
#include <math.h>

#define NN 100000      // nodes
#define NE 1600000     // edges
#define IN_DIM 6
#define EDGE_DIM 2
#define HH 5           // heads
#define CC 5           // channels/head
#define DD 25          // hidden = HH*CC
#define DS 32          // padded fp32 row stride (128B rows)
#define INV_SQRT_C 0.4472135954999579f
#define NBUK 200       // coarse dst buckets
#define BUKW 500       // nodes per bucket (200*500 = 100000 exact)
#define CAP 10000      // slab capacity per bucket (avg 8000, >20 sigma safe)
#define KPB 800        // k_part blocks
#define CH (NE / KPB)  // 2000 edges per k_part block
#define NPB 48         // nodes per block in edge kernel (12 per wave x 4 waves)
#define NBLK ((NN + NPB - 1) / NPB)   // 2084

// q record: 80 B/node (40 shorts). Head h: 16-B chunk at short 40n + 8h = [q0..q4,pad3].
// kv record: 128 B/node (64 shorts), line-aligned. Head h: 16-B chunk at short 64n + 8h
//            = [k0..k4, v0,v1,v2] + 4-B at short 64n + 40 + 2h = [v3,v4].

__device__ __forceinline__ unsigned int f2bf(float f) {   // fp32 -> bf16 bits (RNE)
    unsigned int u = __float_as_uint(f);
    return (u + 0x7fffu + ((u >> 16) & 1u)) >> 16;
}
__device__ __forceinline__ float bflo(unsigned int u) { return __uint_as_float(u << 16); }
__device__ __forceinline__ float bfhi(unsigned int u) { return __uint_as_float(u & 0xffff0000u); }

// ---------------- phase 1: bucket-partition edges (cursor holds per-bucket counts) ----------------
__global__ __launch_bounds__(256) void k_part(const int* __restrict__ ei,
                                              const float* __restrict__ ea,
                                              int* __restrict__ cursor,
                                              uint2* __restrict__ slab) {
    __shared__ int sdst[CH];        // 8 KB
    __shared__ int scnt[NBUK];
    __shared__ int sbase[NBUK];
    __shared__ int swp[NBUK];
    int base = blockIdx.x * CH;
    for (int i = threadIdx.x; i < NBUK; i += 256) scnt[i] = 0;
    __syncthreads();
    for (int i = threadIdx.x; i < CH; i += 256) {
        int dst = ei[NE + base + i];
        sdst[i] = dst;
        atomicAdd(&scnt[dst / BUKW], 1);
    }
    __syncthreads();
    for (int i = threadIdx.x; i < NBUK; i += 256) {
        sbase[i] = i * CAP + atomicAdd(&cursor[i], scnt[i]);
        swp[i] = 0;
    }
    __syncthreads();
    for (int i = threadIdx.x; i < CH; i += 256) {
        int dst = sdst[i];
        int b = dst / BUKW;
        int src = ei[base + i];
        float2 eav = ((const float2*)ea)[base + i];
        int p = sbase[b] + atomicAdd(&swp[b], 1);
        uint2 r;
        r.x = (unsigned)src | ((unsigned)(dst - b * BUKW) << 17);  // src:17b, dstLocal:9b
        r.y = f2bf(eav.x) | (f2bf(eav.y) << 16);
        slab[p] = r;
    }
}

// ---------------- phase 2: bucket offset + hist + scan + rowptr + place (one block/bucket) --------
__global__ __launch_bounds__(512) void k_place(const int* __restrict__ cursor,
                                               const uint2* __restrict__ slab,
                                               int* __restrict__ rowptr,
                                               uint2* __restrict__ csr) {
    __shared__ int hist[BUKW];
    __shared__ int cur[BUKW];
    __shared__ int s[512];
    int b = blockIdx.x;
    int t = threadIdx.x;
    int node0 = b * BUKW;
    int begin = b * CAP;
    int cnt = cursor[b];
    // bucket offset = sum of counts of buckets < b (tree reduce over 200 cursors)
    s[t] = (t < NBUK && t < b) ? cursor[t] : 0;
    __syncthreads();
    for (int off = 256; off > 0; off >>= 1) {
        if (t < off) s[t] += s[t + off];
        __syncthreads();
    }
    int bOff = s[0];
    __syncthreads();
    for (int i = t; i < BUKW; i += 512) hist[i] = 0;
    __syncthreads();
    for (int i = t; i < cnt; i += 512) {
        uint2 r = slab[begin + i];
        atomicAdd(&hist[r.x >> 17], 1);
    }
    __syncthreads();
    int hv = (t < BUKW) ? hist[t] : 0;
    s[t] = hv;
    __syncthreads();
    for (int off = 1; off < 512; off <<= 1) {
        int u = (t >= off) ? s[t - off] : 0;
        __syncthreads();
        s[t] += u;
        __syncthreads();
    }
    if (t < BUKW) {
        int o = bOff + s[t] - hv;
        rowptr[node0 + t] = o;
        cur[t] = o;
    }
    if (b == NBUK - 1 && t == 0) rowptr[NN] = NE;
    __syncthreads();
    for (int i = t; i < cnt; i += 512) {
        uint2 r = slab[begin + i];         // L2 hit (just streamed)
        int dl = (int)(r.x >> 17);
        int p = atomicAdd(&cur[dl], 1);
        uint2 o;
        o.x = r.x & 0x1FFFFu;
        o.y = r.y;
        csr[p] = o;
    }
}

// ---------------- degree counting sort: hist -> scan -> scatter perm ----------------
__global__ void k_deghist(const int* __restrict__ rowptr, int* __restrict__ dhist) {
    __shared__ int lh[256];
    int t = threadIdx.x;
    lh[t] = 0;
    __syncthreads();
    int i = blockIdx.x * 256 + t;
    if (i < NN) {
        int d = rowptr[i + 1] - rowptr[i];
        atomicAdd(&lh[d > 255 ? 255 : d], 1);
    }
    __syncthreads();
    if (lh[t]) atomicAdd(&dhist[t], lh[t]);
}

__global__ void k_degscan(const int* __restrict__ dhist, int* __restrict__ bincur) {
    __shared__ int s[256];
    int t = threadIdx.x;
    int v = dhist[t];
    s[t] = v;
    __syncthreads();
    for (int off = 1; off < 256; off <<= 1) {
        int u = (t >= off) ? s[t - off] : 0;
        __syncthreads();
        s[t] += u;
        __syncthreads();
    }
    bincur[t] = s[t] - v;   // exclusive
}

__global__ void k_degplace(const int* __restrict__ rowptr, int* __restrict__ bincur,
                           int* __restrict__ perm) {
    int i = blockIdx.x * 256 + threadIdx.x;
    if (i >= NN) return;
    int d = rowptr[i + 1] - rowptr[i];
    int p = atomicAdd(&bincur[d > 255 ? 255 : d], 1);
    perm[p] = i;
}

// ---------------- input projection ----------------
__global__ void k_input_proj(const float* __restrict__ x, const float* __restrict__ Wi,
                             const float* __restrict__ bi, float* __restrict__ h) {
    __shared__ float sW[IN_DIM * DD];
    __shared__ float sb[DD];
    int t = threadIdx.x;
    if (t < IN_DIM * DD) sW[t] = Wi[t];
    if (t < DD) sb[t] = bi[t];
    __syncthreads();
    int tid = blockIdx.x * blockDim.x + t;
    int n = tid / DD, d = tid - n * DD;
    if (n >= NN) return;
    float acc = sb[d];
    const float* xr = x + n * IN_DIM;
#pragma unroll
    for (int i = 0; i < IN_DIM; i++) acc += xr[i] * sW[i * DD + d];
    h[n * DS + d] = acc;
}

// ------- per-layer node pass: q (80-B rows), kv (128-B aligned rows), skip in fp32 -------
__global__ void k_qkv_skip(const float* __restrict__ h,
                           const float* __restrict__ Wq, const float* __restrict__ bq,
                           const float* __restrict__ Wk, const float* __restrict__ bk,
                           const float* __restrict__ Wv, const float* __restrict__ bv,
                           const float* __restrict__ Ws, const float* __restrict__ bs,
                           __hip_bfloat16* __restrict__ q, __hip_bfloat16* __restrict__ kv,
                           float* __restrict__ hout) {
    __shared__ float sWq[DD * DD], sWk[DD * DD], sWv[DD * DD], sWs[DD * DD];
    __shared__ float sb[4 * DD];
    for (int i = threadIdx.x; i < DD * DD; i += blockDim.x) {
        sWq[i] = Wq[i]; sWk[i] = Wk[i]; sWv[i] = Wv[i]; sWs[i] = Ws[i];
    }
    if (threadIdx.x < DD) {
        sb[threadIdx.x]          = bq[threadIdx.x];
        sb[DD + threadIdx.x]     = bk[threadIdx.x];
        sb[2 * DD + threadIdx.x] = bv[threadIdx.x];
        sb[3 * DD + threadIdx.x] = bs[threadIdx.x];
    }
    __syncthreads();
    int tid = blockIdx.x * blockDim.x + threadIdx.x;
    int n = tid / DD, d = tid - n * DD;
    if (n >= NN) return;
    float aq = sb[d], ak = sb[DD + d], av = sb[2 * DD + d], asv = sb[3 * DD + d];
    const float* hr = h + (size_t)n * DS;
#pragma unroll
    for (int i = 0; i < DD; i++) {
        float hv = hr[i];
        aq  += hv * sWq[i * DD + d];
        ak  += hv * sWk[i * DD + d];
        av  += hv * sWv[i * DD + d];
        asv += hv * sWs[i * DD + d];
    }
    int h5 = d / 5, c5 = d - 5 * h5;
    q[(size_t)n * 40 + 8 * h5 + c5] = __float2bfloat16(aq * INV_SQRT_C);  // fold 1/sqrt(C)
    size_t rb = (size_t)n * 64;      // 128-B rows
    kv[rb + 8 * h5 + c5] = __float2bfloat16(ak);                          // k0..k4
    if (c5 < 3) kv[rb + 8 * h5 + 5 + c5] = __float2bfloat16(av);          // v0..v2
    else        kv[rb + 40 + 2 * h5 + (c5 - 3)] = __float2bfloat16(av);   // v3,v4
    hout[(size_t)n * DS + d] = asv;
}

// ---------------- fused edge pass: 5 lanes = 5 heads per node (degree-sorted) ----------------
__global__ __launch_bounds__(256) void k_edge_fused(
    const int* __restrict__ rowptr, const uint2* __restrict__ csr,
    const int* __restrict__ perm,
    const float* __restrict__ We, const __hip_bfloat16* __restrict__ q,
    const __hip_bfloat16* __restrict__ kv, float* __restrict__ hout,
    int fuse_head, const float* __restrict__ Wo, const float* __restrict__ bo,
    float* __restrict__ out) {
    __shared__ float sWe[EDGE_DIM * DD];
    __shared__ float sWo[DD];
    __shared__ float sbo;
    if (threadIdx.x < EDGE_DIM * DD) sWe[threadIdx.x] = We[threadIdx.x];
    if (threadIdx.x < DD) sWo[threadIdx.x] = Wo[threadIdx.x];
    if (threadIdx.x == 0) sbo = bo[0];
    __syncthreads();
    int lane = threadIdx.x & 63;
    int wv   = threadIdx.x >> 6;
    int grp  = lane / 5;             // 0..12 (12 = idle lanes 60-63)
    int h    = lane - grp * 5;       // head
    int idx  = blockIdx.x * NPB + wv * 12 + grp;
    bool act = (grp < 12) && (idx < NN);
    int node = 0;

    int beg = 0, end = 0;
    float qa0 = 0, qa1 = 0, qa2 = 0, qa3 = 0, qa4 = 0, qwx = 0, qwy = 0;
    if (act) {
        node = perm[idx];            // degree-sorted: waves get uniform degree
        beg = rowptr[node];
        end = rowptr[node + 1];
        uint4 qc = *(const uint4*)(q + (size_t)node * 40 + 8 * h);  // 16-B aligned
        qa0 = bflo(qc.x); qa1 = bfhi(qc.x); qa2 = bflo(qc.y); qa3 = bfhi(qc.y); qa4 = bflo(qc.z);
        const float* wx = &sWe[5 * h];
        const float* wy = &sWe[DD + 5 * h];
        qwx = qa0 * wx[0] + qa1 * wx[1] + qa2 * wx[2] + qa3 * wx[3] + qa4 * wx[4];
        qwy = qa0 * wy[0] + qa1 * wy[1] + qa2 * wy[2] + qa3 * wy[3] + qa4 * wy[4];
    }

    float l = 0.f, Sx = 0.f, Sy = 0.f;
    float a0 = 0.f, a1 = 0.f, a2 = 0.f, a3 = 0.f, a4 = 0.f;

    int p = beg;
    uint2 rec;
    rec.x = 0; rec.y = 0;
    if (p < end) rec = csr[p];
    while (p < end) {
        int pn = p + 1;
        uint2 nrec = rec;
        if (pn < end) nrec = csr[pn];              // prefetch next record
        const __hip_bfloat16* base = kv + ((size_t)rec.x << 6);     // 128-B row
        uint4 A = *(const uint4*)(base + 8 * h);                    // byte 16h, 16-B aligned
        unsigned int B = *(const unsigned int*)(base + 40 + 2 * h); // byte 80+4h
        float eax = bflo(rec.y), eay = bfhi(rec.y);
        float k0 = bflo(A.x), k1 = bfhi(A.x), k2 = bflo(A.y), k3 = bfhi(A.y), k4 = bflo(A.z);
        float v0 = bfhi(A.z), v1 = bflo(A.w), v2 = bfhi(A.w), v3 = bflo(B), v4 = bfhi(B);
        float s = qa0 * k0 + qa1 * k1 + qa2 * k2 + qa3 * k3 + qa4 * k4
                + eax * qwx + eay * qwy;
        float cf = __expf(s);
        l  += cf;
        Sx += cf * eax;
        Sy += cf * eay;
        a0 += cf * v0; a1 += cf * v1; a2 += cf * v2; a3 += cf * v3; a4 += cf * v4;
        rec = nrec;
        p = pn;
    }

    float dot = 0.f;
    if (act) {
        float inv = 1.0f / (l + 1e-16f);
        const float* wx = &sWe[5 * h];
        const float* wy = &sWe[DD + 5 * h];
        float* ho = hout + (size_t)node * DS + 5 * h;
        float n0 = ho[0] + (a0 + Sx * wx[0] + Sy * wy[0]) * inv;
        float n1 = ho[1] + (a1 + Sx * wx[1] + Sy * wy[1]) * inv;
        float n2 = ho[2] + (a2 + Sx * wx[2] + Sy * wy[2]) * inv;
        float n3 = ho[3] + (a3 + Sx * wx[3] + Sy * wy[3]) * inv;
        float n4 = ho[4] + (a4 + Sx * wx[4] + Sy * wy[4]) * inv;
        ho[0] = n0; ho[1] = n1; ho[2] = n2; ho[3] = n3; ho[4] = n4;
        if (fuse_head) {
            const float* wo = &sWo[5 * h];
            dot = n0 * wo[0] + n1 * wo[1] + n2 * wo[2] + n3 * wo[3] + n4 * wo[4];
        }
    }
    if (fuse_head) {
        // sum the 5 head-lanes of each group (uniform shfl, all 64 lanes execute)
        float dsum = dot;
#pragma unroll
        for (int k = 1; k < 5; k++) dsum += __shfl(dot, (grp * 5 + k) & 63, 64);
        if (act && h == 0) out[node] = 1.0f / (1.0f + __expf(-(dsum + sbo)));
    }
}

extern "C" void kernel_launch(void* const* d_in, const int* in_sizes, int n_in,
                              void* d_out, int out_size, void* d_ws, size_t ws_size,
                              hipStream_t stream) {
    const float* x     = (const float*)d_in[0];
    const int*   ei    = (const int*)d_in[1];     // [2,E]: src=[0..E), dst=[E..2E)
    const float* ea    = (const float*)d_in[2];   // [E,2]
    const float* Wi    = (const float*)d_in[3];
    const float* bi    = (const float*)d_in[4];
    const float* Wq    = (const float*)d_in[5];
    const float* bq    = (const float*)d_in[6];
    const float* Wk    = (const float*)d_in[7];
    const float* bk    = (const float*)d_in[8];
    const float* Wv    = (const float*)d_in[9];
    const float* bv    = (const float*)d_in[10];
    const float* We    = (const float*)d_in[11];
    const float* Wskip = (const float*)d_in[12];
    const float* bskip = (const float*)d_in[13];
    const float* Wo    = (const float*)d_in[14];
    const float* bo    = (const float*)d_in[15];
    float* out = (float*)d_out;
    (void)in_sizes; (void)n_in; (void)out_size; (void)ws_size;

    char* wsb = (char*)d_ws;
    size_t off = 0;
    auto alloc = [&](size_t bytes) {
        void* p = wsb + off;
        off += (bytes + 127) & ~(size_t)127;
        return p;
    };
    uint2* slab   = (uint2*)alloc((size_t)NBUK * CAP * sizeof(uint2));       // 16 MB
    uint2* csr    = (uint2*)alloc((size_t)NE * sizeof(uint2));               // 12.8 MB
    __hip_bfloat16* kvrec = (__hip_bfloat16*)alloc((size_t)NN * 64 * 2);     // 12.8 MB
    __hip_bfloat16* qrec  = (__hip_bfloat16*)alloc((size_t)NN * 40 * 2);     // 8 MB
    float* hA     = (float*)alloc((size_t)NN * DS * sizeof(float));
    float* hB     = (float*)alloc((size_t)NN * DS * sizeof(float));
    int*   rowptr = (int*)alloc((size_t)(NN + 1) * sizeof(int));
    int*   zeroed = (int*)alloc((size_t)(NBUK + 256) * sizeof(int));   // cursor + dhist
    int*   cursor = zeroed;
    int*   dhist  = zeroed + NBUK;
    int*   bincur = (int*)alloc(256 * sizeof(int));
    int*   perm   = (int*)alloc((size_t)NN * sizeof(int));

    dim3 blk(256);
    int gN  = (NN + 255) / 256;         // 391
    int gND = (NN * DD + 255) / 256;    // 9766

    // CSR build + degree sort (every call — ws is re-poisoned)
    hipMemsetAsync(zeroed, 0, (size_t)(NBUK + 256) * sizeof(int), stream);
    k_part<<<KPB, blk, 0, stream>>>(ei, ea, cursor, slab);
    k_place<<<NBUK, dim3(512), 0, stream>>>(cursor, slab, rowptr, csr);
    k_deghist<<<gN, blk, 0, stream>>>(rowptr, dhist);
    k_degscan<<<1, blk, 0, stream>>>(dhist, bincur);
    k_degplace<<<gN, blk, 0, stream>>>(rowptr, bincur, perm);

    k_input_proj<<<gND, blk, 0, stream>>>(x, Wi, bi, hA);

    float* hc = hA;
    float* hn = hB;
    for (int l = 0; l < 3; l++) {
        k_qkv_skip<<<gND, blk, 0, stream>>>(hc,
                                            Wq + (size_t)l * DD * DD, bq + (size_t)l * DD,
                                            Wk + (size_t)l * DD * DD, bk + (size_t)l * DD,
                                            Wv + (size_t)l * DD * DD, bv + (size_t)l * DD,
                                            Wskip + (size_t)l * DD * DD, bskip + (size_t)l * DD,
                                            qrec, kvrec, hn);
        k_edge_fused<<<NBLK, blk, 0, stream>>>(rowptr, csr, perm,
                                               We + (size_t)l * EDGE_DIM * DD,
                                               qrec, kvrec, hn,
                                               (l == 2) ? 1 : 0, Wo, bo, out);
        float* t = hc; hc = hn; hn = t;
    }
}

// Round 10
// 375.586 us; speedup vs baseline: 1.6914x; 1.6914x over previous
//
#include <hip/hip_runtime.h>
#include <hip/hip_bf16.h>
#include <math.h>

#define NN 100000      // nodes
#define NE 1600000     // edges
#define IN_DIM 6
#define EDGE_DIM 2
#define HH 5           // heads
#define CC 5           // channels/head
#define DD 25          // hidden = HH*CC
#define DS 32          // padded fp32 row stride (128B rows)
#define INV_SQRT_C 0.4472135954999579f
#define NBUK 200       // coarse dst buckets
#define BUKW 500       // nodes per bucket (200*500 = 100000 exact)
#define CAP 10000      // slab capacity per bucket (avg 8000, >20 sigma safe)
#define KPB 800        // k_part blocks
#define CH (NE / KPB)  // 2000 edges per k_part block
#define NPB 48         // nodes per block in edge kernel (12 per wave x 4 waves)
#define NBLK ((NN + NPB - 1) / NPB)   // 2084
#define NBD ((NN + 255) / 256)        // 391 degree-sort blocks

// q record: 80 B/node (40 shorts). Head h: 16-B chunk at short 40n + 8h = [q0..q4,pad3].
// kv record: 128 B/node (64 shorts), line-aligned. Head h: 16-B chunk at short 64n + 8h
//            = [k0..k4, v0,v1,v2] + 4-B at short 64n + 40 + 2h = [v3,v4].

__device__ __forceinline__ unsigned int f2bf(float f) {   // fp32 -> bf16 bits (RNE)
    unsigned int u = __float_as_uint(f);
    return (u + 0x7fffu + ((u >> 16) & 1u)) >> 16;
}
__device__ __forceinline__ float bflo(unsigned int u) { return __uint_as_float(u << 16); }
__device__ __forceinline__ float bfhi(unsigned int u) { return __uint_as_float(u & 0xffff0000u); }

// ---------------- phase 1: bucket-partition edges (cursor holds per-bucket counts) ----------------
__global__ __launch_bounds__(256) void k_part(const int* __restrict__ ei,
                                              const float* __restrict__ ea,
                                              int* __restrict__ cursor,
                                              uint2* __restrict__ slab) {
    __shared__ int sdst[CH];        // 8 KB
    __shared__ int scnt[NBUK];
    __shared__ int sbase[NBUK];
    __shared__ int swp[NBUK];
    int base = blockIdx.x * CH;
    for (int i = threadIdx.x; i < NBUK; i += 256) scnt[i] = 0;
    __syncthreads();
    for (int i = threadIdx.x; i < CH; i += 256) {
        int dst = ei[NE + base + i];
        sdst[i] = dst;
        atomicAdd(&scnt[dst / BUKW], 1);
    }
    __syncthreads();
    for (int i = threadIdx.x; i < NBUK; i += 256) {
        sbase[i] = i * CAP + atomicAdd(&cursor[i], scnt[i]);
        swp[i] = 0;
    }
    __syncthreads();
    for (int i = threadIdx.x; i < CH; i += 256) {
        int dst = sdst[i];
        int b = dst / BUKW;
        int src = ei[base + i];
        float2 eav = ((const float2*)ea)[base + i];
        int p = sbase[b] + atomicAdd(&swp[b], 1);
        uint2 r;
        r.x = (unsigned)src | ((unsigned)(dst - b * BUKW) << 17);  // src:17b, dstLocal:9b
        r.y = f2bf(eav.x) | (f2bf(eav.y) << 16);
        slab[p] = r;
    }
}

// ---------------- phase 2: bucket offset + hist + scan + rowptr + place (one block/bucket) --------
__global__ __launch_bounds__(512) void k_place(const int* __restrict__ cursor,
                                               const uint2* __restrict__ slab,
                                               int* __restrict__ rowptr,
                                               uint2* __restrict__ csr) {
    __shared__ int hist[BUKW];
    __shared__ int cur[BUKW];
    __shared__ int s[512];
    int b = blockIdx.x;
    int t = threadIdx.x;
    int node0 = b * BUKW;
    int begin = b * CAP;
    int cnt = cursor[b];
    s[t] = (t < NBUK && t < b) ? cursor[t] : 0;
    __syncthreads();
    for (int off = 256; off > 0; off >>= 1) {
        if (t < off) s[t] += s[t + off];
        __syncthreads();
    }
    int bOff = s[0];
    __syncthreads();
    for (int i = t; i < BUKW; i += 512) hist[i] = 0;
    __syncthreads();
    for (int i = t; i < cnt; i += 512) {
        uint2 r = slab[begin + i];
        atomicAdd(&hist[r.x >> 17], 1);
    }
    __syncthreads();
    int hv = (t < BUKW) ? hist[t] : 0;
    s[t] = hv;
    __syncthreads();
    for (int off = 1; off < 512; off <<= 1) {
        int u = (t >= off) ? s[t - off] : 0;
        __syncthreads();
        s[t] += u;
        __syncthreads();
    }
    if (t < BUKW) {
        int o = bOff + s[t] - hv;
        rowptr[node0 + t] = o;
        cur[t] = o;
    }
    if (b == NBUK - 1 && t == 0) rowptr[NN] = NE;
    __syncthreads();
    for (int i = t; i < cnt; i += 512) {
        uint2 r = slab[begin + i];         // L2 hit (just streamed)
        int dl = (int)(r.x >> 17);
        int p = atomicAdd(&cur[dl], 1);
        uint2 o;
        o.x = r.x & 0x1FFFFu;
        o.y = r.y;
        csr[p] = o;
    }
}

// ---------------- contention-free degree counting sort ----------------
// bhist layout: bin-major [256 bins][NBD blocks]
__global__ void k_dh(const int* __restrict__ rowptr, int* __restrict__ bhist) {
    __shared__ int lh[256];
    int t = threadIdx.x;
    lh[t] = 0;
    __syncthreads();
    int i = blockIdx.x * 256 + t;
    if (i < NN) {
        int d = rowptr[i + 1] - rowptr[i];
        atomicAdd(&lh[d > 255 ? 255 : d], 1);
    }
    __syncthreads();
    bhist[t * NBD + blockIdx.x] = lh[t];
}

// one block per bin: exclusive scan over NBD block-counts; binTot[bin] = total
__global__ __launch_bounds__(512) void k_ds(int* __restrict__ bhist, int* __restrict__ binTot) {
    __shared__ int s[512];
    int bin = blockIdx.x;
    int t = threadIdx.x;
    int v = (t < NBD) ? bhist[bin * NBD + t] : 0;
    s[t] = v;
    __syncthreads();
    for (int off = 1; off < 512; off <<= 1) {
        int u = (t >= off) ? s[t - off] : 0;
        __syncthreads();
        s[t] += u;
        __syncthreads();
    }
    if (t < NBD) bhist[bin * NBD + t] = s[t] - v;   // exclusive within bin
    if (t == 511) binTot[bin] = s[511];
}

__global__ void k_ds2(int* __restrict__ binTot, int* __restrict__ binOff) {
    __shared__ int s[256];
    int t = threadIdx.x;
    int v = binTot[t];
    s[t] = v;
    __syncthreads();
    for (int off = 1; off < 256; off <<= 1) {
        int u = (t >= off) ? s[t - off] : 0;
        __syncthreads();
        s[t] += u;
        __syncthreads();
    }
    binOff[t] = s[t] - v;   // exclusive
}

__global__ void k_dp(const int* __restrict__ rowptr, const int* __restrict__ bhist,
                     const int* __restrict__ binOff, int* __restrict__ perm) {
    __shared__ int lcur[256];
    int t = threadIdx.x;
    lcur[t] = 0;
    __syncthreads();
    int i = blockIdx.x * 256 + t;
    if (i < NN) {
        int d = rowptr[i + 1] - rowptr[i];
        if (d > 255) d = 255;
        int r = atomicAdd(&lcur[d], 1);                    // LDS-local rank
        perm[binOff[d] + bhist[d * NBD + blockIdx.x] + r] = i;
    }
}

// ---------------- input projection ----------------
__global__ void k_input_proj(const float* __restrict__ x, const float* __restrict__ Wi,
                             const float* __restrict__ bi, float* __restrict__ h) {
    __shared__ float sW[IN_DIM * DD];
    __shared__ float sb[DD];
    int t = threadIdx.x;
    if (t < IN_DIM * DD) sW[t] = Wi[t];
    if (t < DD) sb[t] = bi[t];
    __syncthreads();
    int tid = blockIdx.x * blockDim.x + t;
    int n = tid / DD, d = tid - n * DD;
    if (n >= NN) return;
    float acc = sb[d];
    const float* xr = x + n * IN_DIM;
#pragma unroll
    for (int i = 0; i < IN_DIM; i++) acc += xr[i] * sW[i * DD + d];
    h[n * DS + d] = acc;
}

// ------- per-layer node pass: q (80-B rows), kv (128-B aligned rows), skip in fp32 -------
__global__ void k_qkv_skip(const float* __restrict__ h,
                           const float* __restrict__ Wq, const float* __restrict__ bq,
                           const float* __restrict__ Wk, const float* __restrict__ bk,
                           const float* __restrict__ Wv, const float* __restrict__ bv,
                           const float* __restrict__ Ws, const float* __restrict__ bs,
                           __hip_bfloat16* __restrict__ q, __hip_bfloat16* __restrict__ kv,
                           float* __restrict__ hout) {
    __shared__ float sWq[DD * DD], sWk[DD * DD], sWv[DD * DD], sWs[DD * DD];
    __shared__ float sb[4 * DD];
    for (int i = threadIdx.x; i < DD * DD; i += blockDim.x) {
        sWq[i] = Wq[i]; sWk[i] = Wk[i]; sWv[i] = Wv[i]; sWs[i] = Ws[i];
    }
    if (threadIdx.x < DD) {
        sb[threadIdx.x]          = bq[threadIdx.x];
        sb[DD + threadIdx.x]     = bk[threadIdx.x];
        sb[2 * DD + threadIdx.x] = bv[threadIdx.x];
        sb[3 * DD + threadIdx.x] = bs[threadIdx.x];
    }
    __syncthreads();
    int tid = blockIdx.x * blockDim.x + threadIdx.x;
    int n = tid / DD, d = tid - n * DD;
    if (n >= NN) return;
    float aq = sb[d], ak = sb[DD + d], av = sb[2 * DD + d], asv = sb[3 * DD + d];
    const float* hr = h + (size_t)n * DS;
#pragma unroll
    for (int i = 0; i < DD; i++) {
        float hv = hr[i];
        aq  += hv * sWq[i * DD + d];
        ak  += hv * sWk[i * DD + d];
        av  += hv * sWv[i * DD + d];
        asv += hv * sWs[i * DD + d];
    }
    int h5 = d / 5, c5 = d - 5 * h5;
    q[(size_t)n * 40 + 8 * h5 + c5] = __float2bfloat16(aq * INV_SQRT_C);  // fold 1/sqrt(C)
    size_t rb = (size_t)n * 64;      // 128-B rows
    kv[rb + 8 * h5 + c5] = __float2bfloat16(ak);                          // k0..k4
    if (c5 < 3) kv[rb + 8 * h5 + 5 + c5] = __float2bfloat16(av);          // v0..v2
    else        kv[rb + 40 + 2 * h5 + (c5 - 3)] = __float2bfloat16(av);   // v3,v4
    hout[(size_t)n * DS + d] = asv;
}

// ---------------- fused edge pass: 5 lanes = 5 heads per node, degree-sorted, 2-way unroll -------
__global__ __launch_bounds__(256) void k_edge_fused(
    const int* __restrict__ rowptr, const uint2* __restrict__ csr,
    const int* __restrict__ perm,
    const float* __restrict__ We, const __hip_bfloat16* __restrict__ q,
    const __hip_bfloat16* __restrict__ kv, float* __restrict__ hout,
    int fuse_head, const float* __restrict__ Wo, const float* __restrict__ bo,
    float* __restrict__ out) {
    __shared__ float sWe[EDGE_DIM * DD];
    __shared__ float sWo[DD];
    __shared__ float sbo;
    if (threadIdx.x < EDGE_DIM * DD) sWe[threadIdx.x] = We[threadIdx.x];
    if (threadIdx.x < DD) sWo[threadIdx.x] = Wo[threadIdx.x];
    if (threadIdx.x == 0) sbo = bo[0];
    __syncthreads();
    int lane = threadIdx.x & 63;
    int wv   = threadIdx.x >> 6;
    int grp  = lane / 5;             // 0..12 (12 = idle lanes 60-63)
    int h    = lane - grp * 5;       // head
    int idx  = blockIdx.x * NPB + wv * 12 + grp;
    bool act = (grp < 12) && (idx < NN);
    int node = 0;

    int beg = 0, end = 0;
    float qa0 = 0, qa1 = 0, qa2 = 0, qa3 = 0, qa4 = 0, qwx = 0, qwy = 0;
    if (act) {
        node = perm[idx];            // degree-sorted: waves get uniform degree
        beg = rowptr[node];
        end = rowptr[node + 1];
        uint4 qc = *(const uint4*)(q + (size_t)node * 40 + 8 * h);  // 16-B aligned
        qa0 = bflo(qc.x); qa1 = bfhi(qc.x); qa2 = bflo(qc.y); qa3 = bfhi(qc.y); qa4 = bflo(qc.z);
        const float* wx = &sWe[5 * h];
        const float* wy = &sWe[DD + 5 * h];
        qwx = qa0 * wx[0] + qa1 * wx[1] + qa2 * wx[2] + qa3 * wx[3] + qa4 * wx[4];
        qwy = qa0 * wy[0] + qa1 * wy[1] + qa2 * wy[2] + qa3 * wy[3] + qa4 * wy[4];
    }

    float l = 0.f, Sx = 0.f, Sy = 0.f;
    float a0 = 0.f, a1 = 0.f, a2 = 0.f, a3 = 0.f, a4 = 0.f;

    int p = beg;
    for (; p + 2 <= end; p += 2) {           // 2 independent gathers in flight
        uint2 r0 = csr[p];
        uint2 r1 = csr[p + 1];
        const __hip_bfloat16* b0 = kv + ((size_t)r0.x << 6);
        const __hip_bfloat16* b1 = kv + ((size_t)r1.x << 6);
        uint4 A0 = *(const uint4*)(b0 + 8 * h);
        unsigned int B0 = *(const unsigned int*)(b0 + 40 + 2 * h);
        uint4 A1 = *(const uint4*)(b1 + 8 * h);
        unsigned int B1 = *(const unsigned int*)(b1 + 40 + 2 * h);
        {
            float eax = bflo(r0.y), eay = bfhi(r0.y);
            float k0 = bflo(A0.x), k1 = bfhi(A0.x), k2 = bflo(A0.y), k3 = bfhi(A0.y), k4 = bflo(A0.z);
            float v0 = bfhi(A0.z), v1 = bflo(A0.w), v2 = bfhi(A0.w), v3 = bflo(B0), v4 = bfhi(B0);
            float s = qa0 * k0 + qa1 * k1 + qa2 * k2 + qa3 * k3 + qa4 * k4 + eax * qwx + eay * qwy;
            float cf = __expf(s);
            l += cf; Sx += cf * eax; Sy += cf * eay;
            a0 += cf * v0; a1 += cf * v1; a2 += cf * v2; a3 += cf * v3; a4 += cf * v4;
        }
        {
            float eax = bflo(r1.y), eay = bfhi(r1.y);
            float k0 = bflo(A1.x), k1 = bfhi(A1.x), k2 = bflo(A1.y), k3 = bfhi(A1.y), k4 = bflo(A1.z);
            float v0 = bfhi(A1.z), v1 = bflo(A1.w), v2 = bfhi(A1.w), v3 = bflo(B1), v4 = bfhi(B1);
            float s = qa0 * k0 + qa1 * k1 + qa2 * k2 + qa3 * k3 + qa4 * k4 + eax * qwx + eay * qwy;
            float cf = __expf(s);
            l += cf; Sx += cf * eax; Sy += cf * eay;
            a0 += cf * v0; a1 += cf * v1; a2 += cf * v2; a3 += cf * v3; a4 += cf * v4;
        }
    }
    if (p < end) {
        uint2 r0 = csr[p];
        const __hip_bfloat16* b0 = kv + ((size_t)r0.x << 6);
        uint4 A0 = *(const uint4*)(b0 + 8 * h);
        unsigned int B0 = *(const unsigned int*)(b0 + 40 + 2 * h);
        float eax = bflo(r0.y), eay = bfhi(r0.y);
        float k0 = bflo(A0.x), k1 = bfhi(A0.x), k2 = bflo(A0.y), k3 = bfhi(A0.y), k4 = bflo(A0.z);
        float v0 = bfhi(A0.z), v1 = bflo(A0.w), v2 = bfhi(A0.w), v3 = bflo(B0), v4 = bfhi(B0);
        float s = qa0 * k0 + qa1 * k1 + qa2 * k2 + qa3 * k3 + qa4 * k4 + eax * qwx + eay * qwy;
        float cf = __expf(s);
        l += cf; Sx += cf * eax; Sy += cf * eay;
        a0 += cf * v0; a1 += cf * v1; a2 += cf * v2; a3 += cf * v3; a4 += cf * v4;
    }

    float dot = 0.f;
    if (act) {
        float inv = 1.0f / (l + 1e-16f);
        const float* wx = &sWe[5 * h];
        const float* wy = &sWe[DD + 5 * h];
        float* ho = hout + (size_t)node * DS + 5 * h;
        float n0 = ho[0] + (a0 + Sx * wx[0] + Sy * wy[0]) * inv;
        float n1 = ho[1] + (a1 + Sx * wx[1] + Sy * wy[1]) * inv;
        float n2 = ho[2] + (a2 + Sx * wx[2] + Sy * wy[2]) * inv;
        float n3 = ho[3] + (a3 + Sx * wx[3] + Sy * wy[3]) * inv;
        float n4 = ho[4] + (a4 + Sx * wx[4] + Sy * wy[4]) * inv;
        ho[0] = n0; ho[1] = n1; ho[2] = n2; ho[3] = n3; ho[4] = n4;
        if (fuse_head) {
            const float* wo = &sWo[5 * h];
            dot = n0 * wo[0] + n1 * wo[1] + n2 * wo[2] + n3 * wo[3] + n4 * wo[4];
        }
    }
    if (fuse_head) {
        float dsum = dot;
#pragma unroll
        for (int k = 1; k < 5; k++) dsum += __shfl(dot, (grp * 5 + k) & 63, 64);
        if (act && h == 0) out[node] = 1.0f / (1.0f + __expf(-(dsum + sbo)));
    }
}

extern "C" void kernel_launch(void* const* d_in, const int* in_sizes, int n_in,
                              void* d_out, int out_size, void* d_ws, size_t ws_size,
                              hipStream_t stream) {
    const float* x     = (const float*)d_in[0];
    const int*   ei    = (const int*)d_in[1];     // [2,E]: src=[0..E), dst=[E..2E)
    const float* ea    = (const float*)d_in[2];   // [E,2]
    const float* Wi    = (const float*)d_in[3];
    const float* bi    = (const float*)d_in[4];
    const float* Wq    = (const float*)d_in[5];
    const float* bq    = (const float*)d_in[6];
    const float* Wk    = (const float*)d_in[7];
    const float* bk    = (const float*)d_in[8];
    const float* Wv    = (const float*)d_in[9];
    const float* bv    = (const float*)d_in[10];
    const float* We    = (const float*)d_in[11];
    const float* Wskip = (const float*)d_in[12];
    const float* bskip = (const float*)d_in[13];
    const float* Wo    = (const float*)d_in[14];
    const float* bo    = (const float*)d_in[15];
    float* out = (float*)d_out;
    (void)in_sizes; (void)n_in; (void)out_size; (void)ws_size;

    char* wsb = (char*)d_ws;
    size_t off = 0;
    auto alloc = [&](size_t bytes) {
        void* p = wsb + off;
        off += (bytes + 127) & ~(size_t)127;
        return p;
    };
    uint2* slab   = (uint2*)alloc((size_t)NBUK * CAP * sizeof(uint2));       // 16 MB
    uint2* csr    = (uint2*)alloc((size_t)NE * sizeof(uint2));               // 12.8 MB
    __hip_bfloat16* kvrec = (__hip_bfloat16*)alloc((size_t)NN * 64 * 2);     // 12.8 MB
    __hip_bfloat16* qrec  = (__hip_bfloat16*)alloc((size_t)NN * 40 * 2);     // 8 MB
    float* hA     = (float*)alloc((size_t)NN * DS * sizeof(float));
    float* hB     = (float*)alloc((size_t)NN * DS * sizeof(float));
    int*   rowptr = (int*)alloc((size_t)(NN + 1) * sizeof(int));
    int*   cursor = (int*)alloc((size_t)NBUK * sizeof(int));
    int*   bhist  = (int*)alloc((size_t)256 * NBD * sizeof(int));            // 400 KB
    int*   binTot = (int*)alloc(256 * sizeof(int));
    int*   binOff = (int*)alloc(256 * sizeof(int));
    int*   perm   = (int*)alloc((size_t)NN * sizeof(int));

    dim3 blk(256);
    int gND = (NN * DD + 255) / 256;    // 9766

    // CSR build + contention-free degree sort (every call — ws is re-poisoned)
    hipMemsetAsync(cursor, 0, (size_t)NBUK * sizeof(int), stream);
    k_part<<<KPB, blk, 0, stream>>>(ei, ea, cursor, slab);
    k_place<<<NBUK, dim3(512), 0, stream>>>(cursor, slab, rowptr, csr);
    k_dh<<<NBD, blk, 0, stream>>>(rowptr, bhist);
    k_ds<<<256, dim3(512), 0, stream>>>(bhist, binTot);
    k_ds2<<<1, blk, 0, stream>>>(binTot, binOff);
    k_dp<<<NBD, blk, 0, stream>>>(rowptr, bhist, binOff, perm);

    k_input_proj<<<gND, blk, 0, stream>>>(x, Wi, bi, hA);

    float* hc = hA;
    float* hn = hB;
    for (int l = 0; l < 3; l++) {
        k_qkv_skip<<<gND, blk, 0, stream>>>(hc,
                                            Wq + (size_t)l * DD * DD, bq + (size_t)l * DD,
                                            Wk + (size_t)l * DD * DD, bk + (size_t)l * DD,
                                            Wv + (size_t)l * DD * DD, bv + (size_t)l * DD,
                                            Wskip + (size_t)l * DD * DD, bskip + (size_t)l * DD,
                                            qrec, kvrec, hn);
        k_edge_fused<<<NBLK, blk, 0, stream>>>(rowptr, csr, perm,
                                               We + (size_t)l * EDGE_DIM * DD,
                                               qrec, kvrec, hn,
                                               (l == 2) ? 1 : 0, Wo, bo, out);
        float* t = hc; hc = hn; hn = t;
    }
}

// Round 12
// 360.419 us; speedup vs baseline: 1.7626x; 1.0421x over previous
//
#include <hip/hip_runtime.h>
#include <hip/hip_bf16.h>
#include <math.h>

#define NN 100000      // nodes
#define NE 1600000     // edges
#define IN_DIM 6
#define EDGE_DIM 2
#define HH 5           // heads
#define CC 5           // channels/head
#define DD 25          // hidden = HH*CC
#define DS 32          // padded fp32 row stride (128B rows)
#define INV_SQRT_C 0.4472135954999579f
#define NBUK 200       // coarse dst buckets
#define BUKW 500       // nodes per bucket (200*500 = 100000 exact)
#define CAP 10000      // slab capacity per bucket (avg 8000, >20 sigma safe)
#define KPB 800        // k_part blocks
#define CH (NE / KPB)  // 2000 edges per k_part block
#define NPB 48         // nodes per block in edge kernel (12 per wave x 4 waves)
#define NBLK ((NN + NPB - 1) / NPB)   // 2084
#define NBD ((NN + 255) / 256)        // 391 degree-sort blocks
#define CSTR 16        // cursor stride in ints (one cache line per bucket)

// q record: 80 B/node (40 shorts). Head h: 16-B chunk at short 40n + 8h = [q0..q4,pad3].
// kv record: 128 B/node (64 shorts), line-aligned. Head h: 16-B chunk at short 64n + 8h
//            = [k0..k4, v0,v1,v2] + 4-B at short 64n + 40 + 2h = [v3,v4].

__device__ __forceinline__ unsigned int f2bf(float f) {   // fp32 -> bf16 bits (RNE)
    unsigned int u = __float_as_uint(f);
    return (u + 0x7fffu + ((u >> 16) & 1u)) >> 16;
}
__device__ __forceinline__ float bflo(unsigned int u) { return __uint_as_float(u << 16); }
__device__ __forceinline__ float bfhi(unsigned int u) { return __uint_as_float(u & 0xffff0000u); }

// ---------------- phase 1: bucket-partition edges (cursor[16*i] holds bucket count) -------------
__global__ __launch_bounds__(256) void k_part(const int* __restrict__ ei,
                                              const float* __restrict__ ea,
                                              int* __restrict__ cursor,
                                              uint2* __restrict__ slab) {
    __shared__ int sdst[CH];        // 8 KB
    __shared__ int scnt[NBUK];
    __shared__ int sbase[NBUK];
    __shared__ int swp[NBUK];
    int base = blockIdx.x * CH;
    for (int i = threadIdx.x; i < NBUK; i += 256) scnt[i] = 0;
    __syncthreads();
    for (int i = threadIdx.x; i < CH; i += 256) {
        int dst = ei[NE + base + i];
        sdst[i] = dst;
        atomicAdd(&scnt[dst / BUKW], 1);
    }
    __syncthreads();
    for (int i = threadIdx.x; i < NBUK; i += 256) {
        sbase[i] = i * CAP + atomicAdd(&cursor[i * CSTR], scnt[i]);  // line-spread bins
        swp[i] = 0;
    }
    __syncthreads();
    for (int i = threadIdx.x; i < CH; i += 256) {
        int dst = sdst[i];
        int b = dst / BUKW;
        int src = ei[base + i];
        float2 eav = ((const float2*)ea)[base + i];
        int p = sbase[b] + atomicAdd(&swp[b], 1);
        uint2 r;
        r.x = (unsigned)src | ((unsigned)(dst - b * BUKW) << 17);  // src:17b, dstLocal:9b
        r.y = f2bf(eav.x) | (f2bf(eav.y) << 16);
        slab[p] = r;
    }
}

// ---------------- phase 2: bucket offset + hist + scan + rowptr + place (one block/bucket) --------
__global__ __launch_bounds__(512) void k_place(const int* __restrict__ cursor,
                                               const uint2* __restrict__ slab,
                                               int* __restrict__ rowptr,
                                               uint2* __restrict__ csr) {
    __shared__ int hist[BUKW];
    __shared__ int cur[BUKW];
    __shared__ int s[512];
    int b = blockIdx.x;
    int t = threadIdx.x;
    int node0 = b * BUKW;
    int begin = b * CAP;
    int cnt = cursor[b * CSTR];
    s[t] = (t < NBUK && t < b) ? cursor[t * CSTR] : 0;
    __syncthreads();
    for (int off = 256; off > 0; off >>= 1) {
        if (t < off) s[t] += s[t + off];
        __syncthreads();
    }
    int bOff = s[0];
    __syncthreads();
    for (int i = t; i < BUKW; i += 512) hist[i] = 0;
    __syncthreads();
    for (int i = t; i < cnt; i += 512) {
        uint2 r = slab[begin + i];
        atomicAdd(&hist[r.x >> 17], 1);
    }
    __syncthreads();
    int hv = (t < BUKW) ? hist[t] : 0;
    s[t] = hv;
    __syncthreads();
    for (int off = 1; off < 512; off <<= 1) {
        int u = (t >= off) ? s[t - off] : 0;
        __syncthreads();
        s[t] += u;
        __syncthreads();
    }
    if (t < BUKW) {
        int o = bOff + s[t] - hv;
        rowptr[node0 + t] = o;
        cur[t] = o;
    }
    if (b == NBUK - 1 && t == 0) rowptr[NN] = NE;
    __syncthreads();
    for (int i = t; i < cnt; i += 512) {
        uint2 r = slab[begin + i];         // L2 hit (just streamed)
        int dl = (int)(r.x >> 17);
        int p = atomicAdd(&cur[dl], 1);
        uint2 o;
        o.x = r.x & 0x1FFFFu;
        o.y = r.y;
        csr[p] = o;
    }
}

// ---------------- contention-free degree counting sort (descending output order) ----------------
// bhist layout: bin-major [256 bins][NBD blocks]
__global__ void k_dh(const int* __restrict__ rowptr, int* __restrict__ bhist) {
    __shared__ int lh[256];
    int t = threadIdx.x;
    lh[t] = 0;
    __syncthreads();
    int i = blockIdx.x * 256 + t;
    if (i < NN) {
        int d = rowptr[i + 1] - rowptr[i];
        atomicAdd(&lh[d > 255 ? 255 : d], 1);
    }
    __syncthreads();
    bhist[t * NBD + blockIdx.x] = lh[t];
}

__global__ __launch_bounds__(512) void k_ds(int* __restrict__ bhist, int* __restrict__ binTot) {
    __shared__ int s[512];
    int bin = blockIdx.x;
    int t = threadIdx.x;
    int v = (t < NBD) ? bhist[bin * NBD + t] : 0;
    s[t] = v;
    __syncthreads();
    for (int off = 1; off < 512; off <<= 1) {
        int u = (t >= off) ? s[t - off] : 0;
        __syncthreads();
        s[t] += u;
        __syncthreads();
    }
    if (t < NBD) bhist[bin * NBD + t] = s[t] - v;   // exclusive within bin
    if (t == 511) binTot[bin] = s[511];
}

__global__ void k_ds2(int* __restrict__ binTot, int* __restrict__ binOff) {
    __shared__ int s[256];
    int t = threadIdx.x;
    int v = binTot[t];
    s[t] = v;
    __syncthreads();
    for (int off = 1; off < 256; off <<= 1) {
        int u = (t >= off) ? s[t - off] : 0;
        __syncthreads();
        s[t] += u;
        __syncthreads();
    }
    binOff[t] = s[t] - v;   // exclusive (ascending); reversed at placement
}

__global__ void k_dp(const int* __restrict__ rowptr, const int* __restrict__ bhist,
                     const int* __restrict__ binOff, int* __restrict__ perm) {
    __shared__ int lcur[256];
    int t = threadIdx.x;
    lcur[t] = 0;
    __syncthreads();
    int i = blockIdx.x * 256 + t;
    if (i < NN) {
        int d = rowptr[i + 1] - rowptr[i];
        if (d > 255) d = 255;
        int r = atomicAdd(&lcur[d], 1);                    // LDS-local rank
        int pos = binOff[d] + bhist[d * NBD + blockIdx.x] + r;
        perm[NN - 1 - pos] = i;                            // descending: heavy blocks first
    }
}

// ---------------- input projection ----------------
__global__ void k_input_proj(const float* __restrict__ x, const float* __restrict__ Wi,
                             const float* __restrict__ bi, float* __restrict__ h) {
    __shared__ float sW[IN_DIM * DD];
    __shared__ float sb[DD];
    int t = threadIdx.x;
    if (t < IN_DIM * DD) sW[t] = Wi[t];
    if (t < DD) sb[t] = bi[t];
    __syncthreads();
    int tid = blockIdx.x * blockDim.x + t;
    int n = tid / DD, d = tid - n * DD;
    if (n >= NN) return;
    float acc = sb[d];
    const float* xr = x + n * IN_DIM;
#pragma unroll
    for (int i = 0; i < IN_DIM; i++) acc += xr[i] * sW[i * DD + d];
    h[n * DS + d] = acc;
}

// ------- per-layer node pass: q (80-B rows), kv (128-B aligned rows), skip in fp32 -------
__global__ void k_qkv_skip(const float* __restrict__ h,
                           const float* __restrict__ Wq, const float* __restrict__ bq,
                           const float* __restrict__ Wk, const float* __restrict__ bk,
                           const float* __restrict__ Wv, const float* __restrict__ bv,
                           const float* __restrict__ Ws, const float* __restrict__ bs,
                           __hip_bfloat16* __restrict__ q, __hip_bfloat16* __restrict__ kv,
                           float* __restrict__ hout) {
    __shared__ float sWq[DD * DD], sWk[DD * DD], sWv[DD * DD], sWs[DD * DD];
    __shared__ float sb[4 * DD];
    for (int i = threadIdx.x; i < DD * DD; i += blockDim.x) {
        sWq[i] = Wq[i]; sWk[i] = Wk[i]; sWv[i] = Wv[i]; sWs[i] = Ws[i];
    }
    if (threadIdx.x < DD) {
        sb[threadIdx.x]          = bq[threadIdx.x];
        sb[DD + threadIdx.x]     = bk[threadIdx.x];
        sb[2 * DD + threadIdx.x] = bv[threadIdx.x];
        sb[3 * DD + threadIdx.x] = bs[threadIdx.x];
    }
    __syncthreads();
    int tid = blockIdx.x * blockDim.x + threadIdx.x;
    int n = tid / DD, d = tid - n * DD;
    if (n >= NN) return;
    float aq = sb[d], ak = sb[DD + d], av = sb[2 * DD + d], asv = sb[3 * DD + d];
    const float* hr = h + (size_t)n * DS;
#pragma unroll
    for (int i = 0; i < DD; i++) {
        float hv = hr[i];
        aq  += hv * sWq[i * DD + d];
        ak  += hv * sWk[i * DD + d];
        av  += hv * sWv[i * DD + d];
        asv += hv * sWs[i * DD + d];
    }
    int h5 = d / 5, c5 = d - 5 * h5;
    q[(size_t)n * 40 + 8 * h5 + c5] = __float2bfloat16(aq * INV_SQRT_C);  // fold 1/sqrt(C)
    size_t rb = (size_t)n * 64;      // 128-B rows
    kv[rb + 8 * h5 + c5] = __float2bfloat16(ak);                          // k0..k4
    if (c5 < 3) kv[rb + 8 * h5 + 5 + c5] = __float2bfloat16(av);          // v0..v2
    else        kv[rb + 40 + 2 * h5 + (c5 - 3)] = __float2bfloat16(av);   // v3,v4
    hout[(size_t)n * DS + d] = asv;
}

// ---------------- fused edge pass: 5 lanes = 5 heads/node, desc-degree-sorted, 4-way unroll ------
struct EState { float l, Sx, Sy, a0, a1, a2, a3, a4; };

__device__ __forceinline__ void edge_acc(EState& st, uint2 rec, uint4 A, unsigned int B,
                                         float qa0, float qa1, float qa2, float qa3, float qa4,
                                         float qwx, float qwy) {
    float eax = bflo(rec.y), eay = bfhi(rec.y);
    float k0 = bflo(A.x), k1 = bfhi(A.x), k2 = bflo(A.y), k3 = bfhi(A.y), k4 = bflo(A.z);
    float v0 = bfhi(A.z), v1 = bflo(A.w), v2 = bfhi(A.w), v3 = bflo(B), v4 = bfhi(B);
    float s = qa0 * k0 + qa1 * k1 + qa2 * k2 + qa3 * k3 + qa4 * k4 + eax * qwx + eay * qwy;
    float cf = __expf(s);
    st.l += cf; st.Sx += cf * eax; st.Sy += cf * eay;
    st.a0 += cf * v0; st.a1 += cf * v1; st.a2 += cf * v2; st.a3 += cf * v3; st.a4 += cf * v4;
}

__global__ __launch_bounds__(256) void k_edge_fused(
    const int* __restrict__ rowptr, const uint2* __restrict__ csr,
    const int* __restrict__ perm,
    const float* __restrict__ We, const __hip_bfloat16* __restrict__ q,
    const __hip_bfloat16* __restrict__ kv, float* __restrict__ hout,
    int fuse_head, const float* __restrict__ Wo, const float* __restrict__ bo,
    float* __restrict__ out) {
    __shared__ float sWe[EDGE_DIM * DD];
    __shared__ float sWo[DD];
    __shared__ float sbo;
    if (threadIdx.x < EDGE_DIM * DD) sWe[threadIdx.x] = We[threadIdx.x];
    if (threadIdx.x < DD) sWo[threadIdx.x] = Wo[threadIdx.x];
    if (threadIdx.x == 0) sbo = bo[0];
    __syncthreads();
    int lane = threadIdx.x & 63;
    int wv   = threadIdx.x >> 6;
    int grp  = lane / 5;             // 0..12 (12 = idle lanes 60-63)
    int h    = lane - grp * 5;       // head
    int idx  = blockIdx.x * NPB + wv * 12 + grp;
    bool act = (grp < 12) && (idx < NN);
    int node = 0;

    int beg = 0, end = 0;
    float qa0 = 0, qa1 = 0, qa2 = 0, qa3 = 0, qa4 = 0, qwx = 0, qwy = 0;
    if (act) {
        node = perm[idx];            // desc degree: waves uniform, heavy blocks first
        beg = rowptr[node];
        end = rowptr[node + 1];
        uint4 qc = *(const uint4*)(q + (size_t)node * 40 + 8 * h);  // 16-B aligned
        qa0 = bflo(qc.x); qa1 = bfhi(qc.x); qa2 = bflo(qc.y); qa3 = bfhi(qc.y); qa4 = bflo(qc.z);
        const float* wx = &sWe[5 * h];
        const float* wy = &sWe[DD + 5 * h];
        qwx = qa0 * wx[0] + qa1 * wx[1] + qa2 * wx[2] + qa3 * wx[3] + qa4 * wx[4];
        qwy = qa0 * wy[0] + qa1 * wy[1] + qa2 * wy[2] + qa3 * wy[3] + qa4 * wy[4];
    }

    EState st = {0.f, 0.f, 0.f, 0.f, 0.f, 0.f, 0.f, 0.f};

    int p = beg;
    for (; p + 4 <= end; p += 4) {           // 4 independent gathers in flight
        uint2 r0 = csr[p], r1 = csr[p + 1], r2 = csr[p + 2], r3 = csr[p + 3];
        const __hip_bfloat16* b0 = kv + ((size_t)r0.x << 6);
        const __hip_bfloat16* b1 = kv + ((size_t)r1.x << 6);
        const __hip_bfloat16* b2 = kv + ((size_t)r2.x << 6);
        const __hip_bfloat16* b3 = kv + ((size_t)r3.x << 6);
        uint4 A0 = *(const uint4*)(b0 + 8 * h);
        uint4 A1 = *(const uint4*)(b1 + 8 * h);
        uint4 A2 = *(const uint4*)(b2 + 8 * h);
        uint4 A3 = *(const uint4*)(b3 + 8 * h);
        unsigned int B0 = *(const unsigned int*)(b0 + 40 + 2 * h);
        unsigned int B1 = *(const unsigned int*)(b1 + 40 + 2 * h);
        unsigned int B2 = *(const unsigned int*)(b2 + 40 + 2 * h);
        unsigned int B3 = *(const unsigned int*)(b3 + 40 + 2 * h);
        edge_acc(st, r0, A0, B0, qa0, qa1, qa2, qa3, qa4, qwx, qwy);
        edge_acc(st, r1, A1, B1, qa0, qa1, qa2, qa3, qa4, qwx, qwy);
        edge_acc(st, r2, A2, B2, qa0, qa1, qa2, qa3, qa4, qwx, qwy);
        edge_acc(st, r3, A3, B3, qa0, qa1, qa2, qa3, qa4, qwx, qwy);
    }
    for (; p < end; ++p) {
        uint2 r0 = csr[p];
        const __hip_bfloat16* b0 = kv + ((size_t)r0.x << 6);
        uint4 A0 = *(const uint4*)(b0 + 8 * h);
        unsigned int B0 = *(const unsigned int*)(b0 + 40 + 2 * h);
        edge_acc(st, r0, A0, B0, qa0, qa1, qa2, qa3, qa4, qwx, qwy);
    }

    float dot = 0.f;
    if (act) {
        float inv = 1.0f / (st.l + 1e-16f);
        const float* wx = &sWe[5 * h];
        const float* wy = &sWe[DD + 5 * h];
        float* ho = hout + (size_t)node * DS + 5 * h;
        float n0 = ho[0] + (st.a0 + st.Sx * wx[0] + st.Sy * wy[0]) * inv;
        float n1 = ho[1] + (st.a1 + st.Sx * wx[1] + st.Sy * wy[1]) * inv;
        float n2 = ho[2] + (st.a2 + st.Sx * wx[2] + st.Sy * wy[2]) * inv;
        float n3 = ho[3] + (st.a3 + st.Sx * wx[3] + st.Sy * wy[3]) * inv;
        float n4 = ho[4] + (st.a4 + st.Sx * wx[4] + st.Sy * wy[4]) * inv;
        ho[0] = n0; ho[1] = n1; ho[2] = n2; ho[3] = n3; ho[4] = n4;
        if (fuse_head) {
            const float* wo = &sWo[5 * h];
            dot = n0 * wo[0] + n1 * wo[1] + n2 * wo[2] + n3 * wo[3] + n4 * wo[4];
        }
    }
    if (fuse_head) {
        float dsum = dot;
#pragma unroll
        for (int k = 1; k < 5; k++) dsum += __shfl(dot, (grp * 5 + k) & 63, 64);
        if (act && h == 0) out[node] = 1.0f / (1.0f + __expf(-(dsum + sbo)));
    }
}

extern "C" void kernel_launch(void* const* d_in, const int* in_sizes, int n_in,
                              void* d_out, int out_size, void* d_ws, size_t ws_size,
                              hipStream_t stream) {
    const float* x     = (const float*)d_in[0];
    const int*   ei    = (const int*)d_in[1];     // [2,E]: src=[0..E), dst=[E..2E)
    const float* ea    = (const float*)d_in[2];   // [E,2]
    const float* Wi    = (const float*)d_in[3];
    const float* bi    = (const float*)d_in[4];
    const float* Wq    = (const float*)d_in[5];
    const float* bq    = (const float*)d_in[6];
    const float* Wk    = (const float*)d_in[7];
    const float* bk    = (const float*)d_in[8];
    const float* Wv    = (const float*)d_in[9];
    const float* bv    = (const float*)d_in[10];
    const float* We    = (const float*)d_in[11];
    const float* Wskip = (const float*)d_in[12];
    const float* bskip = (const float*)d_in[13];
    const float* Wo    = (const float*)d_in[14];
    const float* bo    = (const float*)d_in[15];
    float* out = (float*)d_out;
    (void)in_sizes; (void)n_in; (void)out_size; (void)ws_size;

    char* wsb = (char*)d_ws;
    size_t off = 0;
    auto alloc = [&](size_t bytes) {
        void* p = wsb + off;
        off += (bytes + 127) & ~(size_t)127;
        return p;
    };
    uint2* slab   = (uint2*)alloc((size_t)NBUK * CAP * sizeof(uint2));       // 16 MB
    uint2* csr    = (uint2*)alloc((size_t)NE * sizeof(uint2));               // 12.8 MB
    __hip_bfloat16* kvrec = (__hip_bfloat16*)alloc((size_t)NN * 64 * 2);     // 12.8 MB
    __hip_bfloat16* qrec  = (__hip_bfloat16*)alloc((size_t)NN * 40 * 2);     // 8 MB
    float* hA     = (float*)alloc((size_t)NN * DS * sizeof(float));
    float* hB     = (float*)alloc((size_t)NN * DS * sizeof(float));
    int*   rowptr = (int*)alloc((size_t)(NN + 1) * sizeof(int));
    int*   cursor = (int*)alloc((size_t)NBUK * CSTR * sizeof(int));          // line-spread
    int*   bhist  = (int*)alloc((size_t)256 * NBD * sizeof(int));            // 400 KB
    int*   binTot = (int*)alloc(256 * sizeof(int));
    int*   binOff = (int*)alloc(256 * sizeof(int));
    int*   perm   = (int*)alloc((size_t)NN * sizeof(int));

    dim3 blk(256);
    int gND = (NN * DD + 255) / 256;    // 9766

    // CSR build + contention-free degree sort (every call — ws is re-poisoned)
    (void)hipMemsetAsync(cursor, 0, (size_t)NBUK * CSTR * sizeof(int), stream);
    k_part<<<KPB, blk, 0, stream>>>(ei, ea, cursor, slab);
    k_place<<<NBUK, dim3(512), 0, stream>>>(cursor, slab, rowptr, csr);
    k_dh<<<NBD, blk, 0, stream>>>(rowptr, bhist);
    k_ds<<<256, dim3(512), 0, stream>>>(bhist, binTot);
    k_ds2<<<1, blk, 0, stream>>>(binTot, binOff);
    k_dp<<<NBD, blk, 0, stream>>>(rowptr, bhist, binOff, perm);

    k_input_proj<<<gND, blk, 0, stream>>>(x, Wi, bi, hA);

    float* hc = hA;
    float* hn = hB;
    for (int l = 0; l < 3; l++) {
        k_qkv_skip<<<gND, blk, 0, stream>>>(hc,
                                            Wq + (size_t)l * DD * DD, bq + (size_t)l * DD,
                                            Wk + (size_t)l * DD * DD, bk + (size_t)l * DD,
                                            Wv + (size_t)l * DD * DD, bv + (size_t)l * DD,
                                            Wskip + (size_t)l * DD * DD, bskip + (size_t)l * DD,
                                            qrec, kvrec, hn);
        k_edge_fused<<<NBLK, blk, 0, stream>>>(rowptr, csr, perm,
                                               We + (size_t)l * EDGE_DIM * DD,
                                               qrec, kvrec, hn,
                                               (l == 2) ? 1 : 0, Wo, bo, out);
        float* t = hc; hc = hn; hn = t;
    }
}